// Round 2
// baseline (41.156 us; speedup 1.0000x reference)
//
#include <hip/hip_runtime.h>

// LocalSelfAttention: bs=4, h=12, s=4096, d=64, BLOCK=64 -> 3072 independent
// 64x64x64 block-attention problems. fp32 in/out. Latency-bound (R0: occ 35%,
// 2.95M bank-conflicts, 2 barriers). R1: single-barrier structure, P exchange
// via in-wave shuffles (no LDS P), LDS 24.8KB -> 6 WG/CU.

typedef __attribute__((ext_vector_type(8))) short bf16x8;   // 8 bf16 = 4 VGPR
typedef __attribute__((ext_vector_type(4))) float f32x4;    // MFMA 16x16 acc
typedef __attribute__((ext_vector_type(4))) unsigned short us4; // 8B LDS store

#define MFMA16(a, b, c) __builtin_amdgcn_mfma_f32_16x16x32_bf16((a), (b), (c), 0, 0, 0)
// XOR swizzle (guide §6 G4): row-major [64][64] bf16 has 128B row stride ->
// column reads are 16-way bank conflicts without this.
#define SWZ(byteoff, row) ((byteoff) ^ (((row) & 7) << 4))

static __device__ __forceinline__ unsigned short f2bf(float x) {
    union { float f; unsigned int u; } v; v.f = x;
    unsigned int r = v.u + 0x7fffu + ((v.u >> 16) & 1u);   // RNE
    return (unsigned short)(r >> 16);
}
static __device__ __forceinline__ float bf2f(unsigned short b) {
    union { float f; unsigned int u; } v; v.u = ((unsigned int)b) << 16;
    return v.f;
}

// One workgroup (256 thr = 4 waves) per (b, h, block). Each wave owns a
// 16-query strip. S^T = K·Q^T (softmax = in-lane 16 + 2 shuffles); P stays
// in registers and is re-fragmented for PV by 16 in-wave shuffles.
__global__ __launch_bounds__(256, 6) void lsa_kernel(
    const float* __restrict__ Q, const float* __restrict__ K,
    const float* __restrict__ V, const float* __restrict__ M,
    float* __restrict__ O)
{
    __shared__ unsigned short Kh[4096];   // K block bf16 hi   [key][d]
    __shared__ unsigned short Kl[4096];   // K block bf16 lo
    __shared__ unsigned short VT[4096];   // V block bf16, transposed: [d][key]
    __shared__ float maskv[64];           // mask values for this block's keys

    const int tid = threadIdx.x;
    const int gid = blockIdx.x;                // (b*12 + h)*64 + blk
    const size_t base = (size_t)gid * 4096;    // contiguous 64x64 fp32 block

    const int lane = tid & 63;
    const int wv   = tid >> 6;      // wave id = query strip (16 rows each)
    const int cc   = lane & 15;
    const int gg   = lane >> 4;
    const int qrow = wv * 16 + cc;  // this lane's query row

    // ---- issue all global loads first (K, V staging + Q fragments) ----
    const float4* Kg = (const float4*)(K + base);
    const float4* Vg = (const float4*)(V + base);
    float4 kv[4], vv[4];
#pragma unroll
    for (int it = 0; it < 4; ++it) {
        int i = tid + it * 256;
        kv[it] = Kg[i];
        vv[it] = Vg[i];
    }
    // Q fragment direct from global: rows wv*16..+16, 2x16B per row half ->
    // coalesced at wave level. Skips LDS entirely.
    bf16x8 qfh[2], qfl[2];
#pragma unroll
    for (int s = 0; s < 2; ++s) {
        const float* qp = Q + base + (size_t)qrow * 64 + s * 32 + gg * 8;
        float4 f0 = *(const float4*)qp;
        float4 f1 = *(const float4*)(qp + 4);
        float f[8] = {f0.x, f0.y, f0.z, f0.w, f1.x, f1.y, f1.z, f1.w};
        bf16x8 h, l;
#pragma unroll
        for (int j = 0; j < 8; ++j) {
            unsigned short hb = f2bf(f[j]);
            h[j] = (short)hb;
            l[j] = (short)f2bf(f[j] - bf2f(hb));   // exact residual
        }
        qfh[s] = h; qfl[s] = l;
    }
    if (tid < 64) {
        int b = gid / 768;          // / (h*nb) = / (12*64)
        int blk = gid & 63;
        maskv[tid] = M[(size_t)b * 4096 + blk * 64 + tid];
    }

    // ---- convert + store K (hi/lo) and V^T into LDS ----
#pragma unroll
    for (int it = 0; it < 4; ++it) {
        int i = tid + it * 256;     // float4 index 0..1023
        int row = i >> 4;           // 16 float4 per 64-float row
        int cb  = (i & 15) * 8;     // byte col (4 bf16 = 8B)
        {
            float4 x = kv[it];
            us4 h, l;
            unsigned short hb;
            hb = f2bf(x.x); h.x = hb; l.x = f2bf(x.x - bf2f(hb));
            hb = f2bf(x.y); h.y = hb; l.y = f2bf(x.y - bf2f(hb));
            hb = f2bf(x.z); h.z = hb; l.z = f2bf(x.z - bf2f(hb));
            hb = f2bf(x.w); h.w = hb; l.w = f2bf(x.w - bf2f(hb));
            int by = SWZ(row * 128 + cb, row);
            *(us4*)((char*)Kh + by) = h;
            *(us4*)((char*)Kl + by) = l;
        }
        {
            float4 x = vv[it];
            int key = row, dbase = (i & 15) * 4;
            float xs[4] = {x.x, x.y, x.z, x.w};
#pragma unroll
            for (int dj = 0; dj < 4; ++dj) {
                int d = dbase + dj;
                *(unsigned short*)((char*)VT + SWZ(d * 128 + key * 2, d)) = f2bf(xs[dj]);
            }
        }
    }
    __syncthreads();   // the ONLY barrier: Kh/Kl/VT/mask never overwritten

    // ---- scores: S^T[key][q] = sum_d K[key][d] * Q[q][d]  (hi/lo 3-term) ----
    // C/D layout (m89-verified): col = lane&15 = q, row-local key = gg*4+reg.
    float sc[16];
#pragma unroll
    for (int kt = 0; kt < 4; ++kt) {
        f32x4 acc = {0.f, 0.f, 0.f, 0.f};
        int krow = kt * 16 + cc;
#pragma unroll
        for (int s = 0; s < 2; ++s) {
            int by = SWZ(krow * 128 + s * 64 + gg * 16, krow);
            bf16x8 ah = *(bf16x8*)((char*)Kh + by);
            bf16x8 al = *(bf16x8*)((char*)Kl + by);
            acc = MFMA16(ah, qfh[s], acc);
            acc = MFMA16(ah, qfl[s], acc);
            acc = MFMA16(al, qfh[s], acc);
        }
#pragma unroll
        for (int r = 0; r < 4; ++r) sc[kt * 4 + r] = acc[r];
    }

    // ---- mask + softmax over keys (this lane: one query, 16 of 64 keys) ----
    float mx = -3.0e38f;
#pragma unroll
    for (int kt = 0; kt < 4; ++kt)
#pragma unroll
        for (int r = 0; r < 4; ++r) {
            int key = kt * 16 + gg * 4 + r;
            float sv = sc[kt * 4 + r] + (maskv[key] == 0.f ? -10000.f : 0.f);
            sc[kt * 4 + r] = sv;
            mx = fmaxf(mx, sv);
        }
    mx = fmaxf(mx, __shfl_xor(mx, 16));
    mx = fmaxf(mx, __shfl_xor(mx, 32));
    float sum = 0.f;
#pragma unroll
    for (int i = 0; i < 16; ++i) { sc[i] = __expf(sc[i] - mx); sum += sc[i]; }
    sum += __shfl_xor(sum, 16);
    sum += __shfl_xor(sum, 32);
    float inv = (maskv[qrow] == 0.f ? 0.f : 1.f) / sum;   // q_removed -> 0 row

    // ---- P re-fragmentation IN-WAVE (no LDS, no barrier) ----
    // Lane (cc,gg) holds P[q=cc][kt*16+gg*4+r]; PV A-frag element j must be
    // P[q=cc][kappa = s*32+gg*8+j] (positionally matching the VT B-frag).
    // kappa's holder: kt' = 2s+(gg>>1), src lane gg_src = (2gg + (j>>2)) & 3.
    unsigned int pku[8];   // pku[kt*2+w]: bf16 pair (r=2w, 2w+1) of kt-group
#pragma unroll
    for (int kt = 0; kt < 4; ++kt) {
        unsigned int e0 = f2bf(sc[kt * 4 + 0] * inv);
        unsigned int e1 = f2bf(sc[kt * 4 + 1] * inv);
        unsigned int e2 = f2bf(sc[kt * 4 + 2] * inv);
        unsigned int e3 = f2bf(sc[kt * 4 + 3] * inv);
        pku[kt * 2 + 0] = e0 | (e1 << 16);
        pku[kt * 2 + 1] = e2 | (e3 << 16);
    }
    const int src0 = ((2 * gg) & 3) * 16 + cc;       // holder of j=0..3
    const int src1 = ((2 * gg + 1) & 3) * 16 + cc;   // holder of j=4..7
    const bool sel = (gg >> 1) & 1;                  // kt' = 2s + sel
    bf16x8 pf[2];
#pragma unroll
    for (int s = 0; s < 2; ++s) {
        unsigned int a0 = (unsigned)__shfl((int)pku[4 * s + 0], src0);
        unsigned int a1 = (unsigned)__shfl((int)pku[4 * s + 1], src0);
        unsigned int b0 = (unsigned)__shfl((int)pku[4 * s + 2], src0);
        unsigned int b1 = (unsigned)__shfl((int)pku[4 * s + 3], src0);
        unsigned int c0 = (unsigned)__shfl((int)pku[4 * s + 0], src1);
        unsigned int c1 = (unsigned)__shfl((int)pku[4 * s + 1], src1);
        unsigned int d0 = (unsigned)__shfl((int)pku[4 * s + 2], src1);
        unsigned int d1 = (unsigned)__shfl((int)pku[4 * s + 3], src1);
        union { unsigned int w[4]; bf16x8 v; } u;
        u.w[0] = sel ? b0 : a0;
        u.w[1] = sel ? b1 : a1;
        u.w[2] = sel ? d0 : c0;
        u.w[3] = sel ? d1 : c1;
        pf[s] = u.v;
    }

    // ---- O = P · V  via A=P (row=q), B=V^T rows (contiguous keys) ----
    float* Ob = O + base;
#pragma unroll
    for (int dt = 0; dt < 4; ++dt) {
        f32x4 o = {0.f, 0.f, 0.f, 0.f};
#pragma unroll
        for (int s = 0; s < 2; ++s) {
            int vr = dt * 16 + cc;
            bf16x8 vb = *(bf16x8*)((char*)VT + SWZ(vr * 128 + s * 64 + gg * 16, vr));
            o = MFMA16(pf[s], vb, o);
        }
#pragma unroll
        for (int r = 0; r < 4; ++r) {
            int q = wv * 16 + gg * 4 + r;   // D-layout row -> query
            Ob[q * 64 + dt * 16 + cc] = o[r];
        }
    }
}

extern "C" void kernel_launch(void* const* d_in, const int* in_sizes, int n_in,
                              void* d_out, int out_size, void* d_ws, size_t ws_size,
                              hipStream_t stream) {
    const float* Q = (const float*)d_in[0];
    const float* K = (const float*)d_in[1];
    const float* V = (const float*)d_in[2];
    const float* M = (const float*)d_in[3];
    float* O = (float*)d_out;
    // bs=4, h=12, s=4096, d=64, BLOCK=64 -> 3072 blocks of 64x64 fp32
    int grid = in_sizes[0] / 4096;   // = 3072
    lsa_kernel<<<grid, 256, 0, stream>>>(Q, K, V, M, O);
}

// Round 3
// 36.646 us; speedup vs baseline: 1.1231x; 1.1231x over previous
//
#include <hip/hip_runtime.h>

// LocalSelfAttention: bs=4, h=12, s=4096, d=64, BLOCK=64 -> 3072 independent
// 64x64x64 block-attention problems. fp32 in/out.
// R0: 35.9us, occ 35% (4 WG/CU), 2 barriers.
// R1: single barrier + in-wave P shuffles, but __launch_bounds__(256,6)
//     forced VGPR 52->40 -> spills (+22MB scratch TCC traffic) -> 41.2us.
// R2: same structure, unconstrained regalloc (LDS 24.8KB still gives 6 WG/CU).

typedef __attribute__((ext_vector_type(8))) short bf16x8;   // 8 bf16 = 4 VGPR
typedef __attribute__((ext_vector_type(4))) float f32x4;    // MFMA 16x16 acc
typedef __attribute__((ext_vector_type(4))) unsigned short us4; // 8B LDS store

#define MFMA16(a, b, c) __builtin_amdgcn_mfma_f32_16x16x32_bf16((a), (b), (c), 0, 0, 0)
// XOR swizzle (guide §6 G4): row-major [64][64] bf16 has 128B row stride ->
// column reads are 16-way bank conflicts without this.
#define SWZ(byteoff, row) ((byteoff) ^ (((row) & 7) << 4))

static __device__ __forceinline__ unsigned short f2bf(float x) {
    union { float f; unsigned int u; } v; v.f = x;
    unsigned int r = v.u + 0x7fffu + ((v.u >> 16) & 1u);   // RNE
    return (unsigned short)(r >> 16);
}
static __device__ __forceinline__ float bf2f(unsigned short b) {
    union { float f; unsigned int u; } v; v.u = ((unsigned int)b) << 16;
    return v.f;
}

// One workgroup (256 thr = 4 waves) per (b, h, block). Each wave owns a
// 16-query strip. S^T = K·Q^T (softmax = in-lane 16 + 2 shuffles); P stays
// in registers and is re-fragmented for PV by 16 in-wave shuffles.
__global__ __launch_bounds__(256) void lsa_kernel(
    const float* __restrict__ Q, const float* __restrict__ K,
    const float* __restrict__ V, const float* __restrict__ M,
    float* __restrict__ O)
{
    __shared__ unsigned short Kh[4096];   // K block bf16 hi   [key][d]
    __shared__ unsigned short Kl[4096];   // K block bf16 lo
    __shared__ unsigned short VT[4096];   // V block bf16, transposed: [d][key]
    __shared__ float maskv[64];           // mask values for this block's keys

    const int tid = threadIdx.x;
    const int gid = blockIdx.x;                // (b*12 + h)*64 + blk
    const size_t base = (size_t)gid * 4096;    // contiguous 64x64 fp32 block

    const int lane = tid & 63;
    const int wv   = tid >> 6;      // wave id = query strip (16 rows each)
    const int cc   = lane & 15;
    const int gg   = lane >> 4;
    const int qrow = wv * 16 + cc;  // this lane's query row

    // ---- issue all global loads first (K, V staging + Q fragments) ----
    const float4* Kg = (const float4*)(K + base);
    const float4* Vg = (const float4*)(V + base);
    float4 kv[4], vv[4];
#pragma unroll
    for (int it = 0; it < 4; ++it) {
        int i = tid + it * 256;
        kv[it] = Kg[i];
        vv[it] = Vg[i];
    }
    // Q fragment direct from global: rows wv*16..+16, 2x16B per row half ->
    // coalesced at wave level. Skips LDS entirely.
    bf16x8 qfh[2], qfl[2];
#pragma unroll
    for (int s = 0; s < 2; ++s) {
        const float* qp = Q + base + (size_t)qrow * 64 + s * 32 + gg * 8;
        float4 f0 = *(const float4*)qp;
        float4 f1 = *(const float4*)(qp + 4);
        float f[8] = {f0.x, f0.y, f0.z, f0.w, f1.x, f1.y, f1.z, f1.w};
        bf16x8 h, l;
#pragma unroll
        for (int j = 0; j < 8; ++j) {
            unsigned short hb = f2bf(f[j]);
            h[j] = (short)hb;
            l[j] = (short)f2bf(f[j] - bf2f(hb));   // exact residual
        }
        qfh[s] = h; qfl[s] = l;
    }
    if (tid < 64) {
        int b = gid / 768;          // / (h*nb) = / (12*64)
        int blk = gid & 63;
        maskv[tid] = M[(size_t)b * 4096 + blk * 64 + tid];
    }

    // ---- convert + store K (hi/lo) and V^T into LDS ----
#pragma unroll
    for (int it = 0; it < 4; ++it) {
        int i = tid + it * 256;     // float4 index 0..1023
        int row = i >> 4;           // 16 float4 per 64-float row
        int cb  = (i & 15) * 8;     // byte col (4 bf16 = 8B)
        {
            float4 x = kv[it];
            us4 h, l;
            unsigned short hb;
            hb = f2bf(x.x); h.x = hb; l.x = f2bf(x.x - bf2f(hb));
            hb = f2bf(x.y); h.y = hb; l.y = f2bf(x.y - bf2f(hb));
            hb = f2bf(x.z); h.z = hb; l.z = f2bf(x.z - bf2f(hb));
            hb = f2bf(x.w); h.w = hb; l.w = f2bf(x.w - bf2f(hb));
            int by = SWZ(row * 128 + cb, row);
            *(us4*)((char*)Kh + by) = h;
            *(us4*)((char*)Kl + by) = l;
        }
        {
            float4 x = vv[it];
            int key = row, dbase = (i & 15) * 4;
            float xs[4] = {x.x, x.y, x.z, x.w};
#pragma unroll
            for (int dj = 0; dj < 4; ++dj) {
                int d = dbase + dj;
                *(unsigned short*)((char*)VT + SWZ(d * 128 + key * 2, d)) = f2bf(xs[dj]);
            }
        }
    }
    __syncthreads();   // the ONLY barrier: Kh/Kl/VT/mask never overwritten

    // ---- scores: S^T[key][q] = sum_d K[key][d] * Q[q][d]  (hi/lo 3-term) ----
    // C/D layout (m89-verified): col = lane&15 = q, row-local key = gg*4+reg.
    float sc[16];
#pragma unroll
    for (int kt = 0; kt < 4; ++kt) {
        f32x4 acc = {0.f, 0.f, 0.f, 0.f};
        int krow = kt * 16 + cc;
#pragma unroll
        for (int s = 0; s < 2; ++s) {
            int by = SWZ(krow * 128 + s * 64 + gg * 16, krow);
            bf16x8 ah = *(bf16x8*)((char*)Kh + by);
            bf16x8 al = *(bf16x8*)((char*)Kl + by);
            acc = MFMA16(ah, qfh[s], acc);
            acc = MFMA16(ah, qfl[s], acc);
            acc = MFMA16(al, qfh[s], acc);
        }
#pragma unroll
        for (int r = 0; r < 4; ++r) sc[kt * 4 + r] = acc[r];
    }

    // ---- mask + softmax over keys (this lane: one query, 16 of 64 keys) ----
    float mx = -3.0e38f;
#pragma unroll
    for (int kt = 0; kt < 4; ++kt)
#pragma unroll
        for (int r = 0; r < 4; ++r) {
            int key = kt * 16 + gg * 4 + r;
            float sv = sc[kt * 4 + r] + (maskv[key] == 0.f ? -10000.f : 0.f);
            sc[kt * 4 + r] = sv;
            mx = fmaxf(mx, sv);
        }
    mx = fmaxf(mx, __shfl_xor(mx, 16));
    mx = fmaxf(mx, __shfl_xor(mx, 32));
    float sum = 0.f;
#pragma unroll
    for (int i = 0; i < 16; ++i) { sc[i] = __expf(sc[i] - mx); sum += sc[i]; }
    sum += __shfl_xor(sum, 16);
    sum += __shfl_xor(sum, 32);
    float inv = (maskv[qrow] == 0.f ? 0.f : 1.f) / sum;   // q_removed -> 0 row

    // ---- P re-fragmentation IN-WAVE (no LDS, no barrier) ----
    // Lane (cc,gg) holds P[q=cc][kt*16+gg*4+r]; PV A-frag element j must be
    // P[q=cc][kappa = s*32+gg*8+j] (positionally matching the VT B-frag).
    // kappa's holder: kt' = 2s+(gg>>1), src lane gg_src = (2gg + (j>>2)) & 3.
    unsigned int pku[8];   // pku[kt*2+w]: bf16 pair (r=2w, 2w+1) of kt-group
#pragma unroll
    for (int kt = 0; kt < 4; ++kt) {
        unsigned int e0 = f2bf(sc[kt * 4 + 0] * inv);
        unsigned int e1 = f2bf(sc[kt * 4 + 1] * inv);
        unsigned int e2 = f2bf(sc[kt * 4 + 2] * inv);
        unsigned int e3 = f2bf(sc[kt * 4 + 3] * inv);
        pku[kt * 2 + 0] = e0 | (e1 << 16);
        pku[kt * 2 + 1] = e2 | (e3 << 16);
    }
    const int src0 = ((2 * gg) & 3) * 16 + cc;       // holder of j=0..3
    const int src1 = ((2 * gg + 1) & 3) * 16 + cc;   // holder of j=4..7
    const bool sel = (gg >> 1) & 1;                  // kt' = 2s + sel
    bf16x8 pf[2];
#pragma unroll
    for (int s = 0; s < 2; ++s) {
        unsigned int a0 = (unsigned)__shfl((int)pku[4 * s + 0], src0);
        unsigned int a1 = (unsigned)__shfl((int)pku[4 * s + 1], src0);
        unsigned int b0 = (unsigned)__shfl((int)pku[4 * s + 2], src0);
        unsigned int b1 = (unsigned)__shfl((int)pku[4 * s + 3], src0);
        unsigned int c0 = (unsigned)__shfl((int)pku[4 * s + 0], src1);
        unsigned int c1 = (unsigned)__shfl((int)pku[4 * s + 1], src1);
        unsigned int d0 = (unsigned)__shfl((int)pku[4 * s + 2], src1);
        unsigned int d1 = (unsigned)__shfl((int)pku[4 * s + 3], src1);
        union { unsigned int w[4]; bf16x8 v; } u;
        u.w[0] = sel ? b0 : a0;
        u.w[1] = sel ? b1 : a1;
        u.w[2] = sel ? d0 : c0;
        u.w[3] = sel ? d1 : c1;
        pf[s] = u.v;
    }

    // ---- O = P · V  via A=P (row=q), B=V^T rows (contiguous keys) ----
    float* Ob = O + base;
#pragma unroll
    for (int dt = 0; dt < 4; ++dt) {
        f32x4 o = {0.f, 0.f, 0.f, 0.f};
#pragma unroll
        for (int s = 0; s < 2; ++s) {
            int vr = dt * 16 + cc;
            bf16x8 vb = *(bf16x8*)((char*)VT + SWZ(vr * 128 + s * 64 + gg * 16, vr));
            o = MFMA16(pf[s], vb, o);
        }
#pragma unroll
        for (int r = 0; r < 4; ++r) {
            int q = wv * 16 + gg * 4 + r;   // D-layout row -> query
            Ob[q * 64 + dt * 16 + cc] = o[r];
        }
    }
}

extern "C" void kernel_launch(void* const* d_in, const int* in_sizes, int n_in,
                              void* d_out, int out_size, void* d_ws, size_t ws_size,
                              hipStream_t stream) {
    const float* Q = (const float*)d_in[0];
    const float* K = (const float*)d_in[1];
    const float* V = (const float*)d_in[2];
    const float* M = (const float*)d_in[3];
    float* O = (float*)d_out;
    // bs=4, h=12, s=4096, d=64, BLOCK=64 -> 3072 blocks of 64x64 fp32
    int grid = in_sizes[0] / 4096;   // = 3072
    lsa_kernel<<<grid, 256, 0, stream>>>(Q, K, V, M, O);
}

// Round 4
// 36.320 us; speedup vs baseline: 1.1332x; 1.0090x over previous
//
#include <hip/hip_runtime.h>

// LocalSelfAttention: bs=4, h=12, s=4096, d=64, BLOCK=64 -> 3072 independent
// 64x64x64 block-attention problems. fp32 in/out.
// R0: 35.9us (occ 35%, 2 barriers). R1: 41.2us (launch_bounds spills).
// R2: 36.6us (occ 44%, 1 barrier, no spills) -> occupancy/barriers NOT the
//     bottleneck; latency-bound with cold-start per WG.
// R3: persistent pipelined WGs: grid=768 (exactly 3 WG/CU, LDS-capped),
//     4 blocks per WG, double-buffered LDS staging, T14 issue-early/
//     write-late prefetch. One barrier per block, loads always in flight.

typedef __attribute__((ext_vector_type(8))) short bf16x8;   // 8 bf16 = 4 VGPR
typedef __attribute__((ext_vector_type(4))) float f32x4;    // MFMA 16x16 acc
typedef __attribute__((ext_vector_type(4))) unsigned short us4; // 8B LDS store

#define MFMA16(a, b, c) __builtin_amdgcn_mfma_f32_16x16x32_bf16((a), (b), (c), 0, 0, 0)
// XOR swizzle (guide §6 G4): row-major [64][64] bf16 has 128B row stride ->
// column reads are 16-way bank conflicts without this.
#define SWZ(byteoff, row) ((byteoff) ^ (((row) & 7) << 4))

static __device__ __forceinline__ unsigned short f2bf(float x) {
    union { float f; unsigned int u; } v; v.f = x;
    unsigned int r = v.u + 0x7fffu + ((v.u >> 16) & 1u);   // RNE
    return (unsigned short)(r >> 16);
}
static __device__ __forceinline__ float bf2f(unsigned short b) {
    union { float f; unsigned int u; } v; v.u = ((unsigned int)b) << 16;
    return v.f;
}

__global__ __launch_bounds__(256) void lsa_kernel(
    const float* __restrict__ Q, const float* __restrict__ K,
    const float* __restrict__ V, const float* __restrict__ M,
    float* __restrict__ O)
{
    __shared__ unsigned short Kh[2][4096];  // K bf16 hi  [key][d], dbl-buffered
    __shared__ unsigned short Kl[2][4096];  // K bf16 lo
    __shared__ unsigned short VT[2][4096];  // V bf16 transposed [d][key]
    __shared__ float maskv[2][64];          // per-block key mask

    const int tid  = threadIdx.x;
    const int lane = tid & 63;
    const int wv   = tid >> 6;      // wave id = 16-query strip
    const int cc   = lane & 15;
    const int gg   = lane >> 4;
    const int qrow = wv * 16 + cc;

    const int blk0 = blockIdx.x * 4;   // 4 consecutive attention blocks per WG

    float4 kv[4], vv[4], qv[4];
    float  mreg;
    bf16x8 qfh[2], qfl[2];

    // ---- issue global loads for one block (registers only, no waits) ----
    auto issue = [&](int blkid) {
        const size_t base = (size_t)blkid * 4096;
        const float4* Kg = (const float4*)(K + base);
        const float4* Vg = (const float4*)(V + base);
#pragma unroll
        for (int it = 0; it < 4; ++it) {
            kv[it] = Kg[tid + it * 256];
            vv[it] = Vg[tid + it * 256];
        }
        const float* qb = Q + base + (size_t)qrow * 64;
        qv[0] = *(const float4*)(qb + gg * 8);
        qv[1] = *(const float4*)(qb + gg * 8 + 4);
        qv[2] = *(const float4*)(qb + 32 + gg * 8);
        qv[3] = *(const float4*)(qb + 32 + gg * 8 + 4);
        int b  = blkid / 768;       // / (h * nb) = / (12*64)
        int bi = blkid & 63;
        mreg = M[(size_t)b * 4096 + bi * 64 + lane];
    };

    // ---- convert kv/vv/mreg and publish into LDS set `buf` ----
    auto stageKV = [&](int buf) {
#pragma unroll
        for (int it = 0; it < 4; ++it) {
            int i   = tid + it * 256;   // float4 index 0..1023
            int row = i >> 4;
            int cb  = (i & 15) * 8;
            {
                float4 x = kv[it];
                us4 h, l;
                unsigned short hb;
                hb = f2bf(x.x); h.x = hb; l.x = f2bf(x.x - bf2f(hb));
                hb = f2bf(x.y); h.y = hb; l.y = f2bf(x.y - bf2f(hb));
                hb = f2bf(x.z); h.z = hb; l.z = f2bf(x.z - bf2f(hb));
                hb = f2bf(x.w); h.w = hb; l.w = f2bf(x.w - bf2f(hb));
                int by = SWZ(row * 128 + cb, row);
                *(us4*)((char*)&Kh[buf][0] + by) = h;
                *(us4*)((char*)&Kl[buf][0] + by) = l;
            }
            {
                float4 x = vv[it];
                int key = row, dbase = (i & 15) * 4;
                float xs[4] = {x.x, x.y, x.z, x.w};
#pragma unroll
                for (int dj = 0; dj < 4; ++dj) {
                    int d = dbase + dj;
                    *(unsigned short*)((char*)&VT[buf][0] + SWZ(d * 128 + key * 2, d)) = f2bf(xs[dj]);
                }
            }
        }
        if (tid < 64) maskv[buf][tid] = mreg;
    };

    // ---- convert qv -> hi/lo fragments (register-private, no barrier) ----
    auto stageQ = [&]() {
#pragma unroll
        for (int s = 0; s < 2; ++s) {
            float4 f0 = qv[2 * s], f1 = qv[2 * s + 1];
            float f[8] = {f0.x, f0.y, f0.z, f0.w, f1.x, f1.y, f1.z, f1.w};
            bf16x8 h, l;
#pragma unroll
            for (int j = 0; j < 8; ++j) {
                unsigned short hb = f2bf(f[j]);
                h[j] = (short)hb;
                l[j] = (short)f2bf(f[j] - bf2f(hb));
            }
            qfh[s] = h; qfl[s] = l;
        }
    };

    // ---- full per-block compute from LDS set `buf` ----
    auto compute = [&](int buf, int blkid) {
        // S^T = K·Q^T (hi/lo 3-term). C layout: col=lane&15=q, key=gg*4+reg.
        float sc[16];
#pragma unroll
        for (int kt = 0; kt < 4; ++kt) {
            f32x4 acc = {0.f, 0.f, 0.f, 0.f};
            int krow = kt * 16 + cc;
#pragma unroll
            for (int s = 0; s < 2; ++s) {
                int by = SWZ(krow * 128 + s * 64 + gg * 16, krow);
                bf16x8 ah = *(bf16x8*)((char*)&Kh[buf][0] + by);
                bf16x8 al = *(bf16x8*)((char*)&Kl[buf][0] + by);
                acc = MFMA16(ah, qfh[s], acc);
                acc = MFMA16(ah, qfl[s], acc);
                acc = MFMA16(al, qfh[s], acc);
            }
#pragma unroll
            for (int r = 0; r < 4; ++r) sc[kt * 4 + r] = acc[r];
        }
        // mask + softmax (lane holds 16 keys of one query; 2 shuffles)
        float mx = -3.0e38f;
#pragma unroll
        for (int kt = 0; kt < 4; ++kt)
#pragma unroll
            for (int r = 0; r < 4; ++r) {
                int key = kt * 16 + gg * 4 + r;
                float sv = sc[kt * 4 + r] + (maskv[buf][key] == 0.f ? -10000.f : 0.f);
                sc[kt * 4 + r] = sv;
                mx = fmaxf(mx, sv);
            }
        mx = fmaxf(mx, __shfl_xor(mx, 16));
        mx = fmaxf(mx, __shfl_xor(mx, 32));
        float sum = 0.f;
#pragma unroll
        for (int i = 0; i < 16; ++i) { sc[i] = __expf(sc[i] - mx); sum += sc[i]; }
        sum += __shfl_xor(sum, 16);
        sum += __shfl_xor(sum, 32);
        float inv = (maskv[buf][qrow] == 0.f ? 0.f : 1.f) / sum;

        // P re-fragmentation in-wave (see R1 derivation)
        unsigned int pku[8];
#pragma unroll
        for (int kt = 0; kt < 4; ++kt) {
            unsigned int e0 = f2bf(sc[kt * 4 + 0] * inv);
            unsigned int e1 = f2bf(sc[kt * 4 + 1] * inv);
            unsigned int e2 = f2bf(sc[kt * 4 + 2] * inv);
            unsigned int e3 = f2bf(sc[kt * 4 + 3] * inv);
            pku[kt * 2 + 0] = e0 | (e1 << 16);
            pku[kt * 2 + 1] = e2 | (e3 << 16);
        }
        const int src0 = ((2 * gg) & 3) * 16 + cc;
        const int src1 = ((2 * gg + 1) & 3) * 16 + cc;
        const bool sel = (gg >> 1) & 1;
        bf16x8 pf[2];
#pragma unroll
        for (int s = 0; s < 2; ++s) {
            unsigned int a0 = (unsigned)__shfl((int)pku[4 * s + 0], src0);
            unsigned int a1 = (unsigned)__shfl((int)pku[4 * s + 1], src0);
            unsigned int b0 = (unsigned)__shfl((int)pku[4 * s + 2], src0);
            unsigned int b1 = (unsigned)__shfl((int)pku[4 * s + 3], src0);
            unsigned int c0 = (unsigned)__shfl((int)pku[4 * s + 0], src1);
            unsigned int c1 = (unsigned)__shfl((int)pku[4 * s + 1], src1);
            unsigned int d0 = (unsigned)__shfl((int)pku[4 * s + 2], src1);
            unsigned int d1 = (unsigned)__shfl((int)pku[4 * s + 3], src1);
            union { unsigned int w[4]; bf16x8 v; } u;
            u.w[0] = sel ? b0 : a0;
            u.w[1] = sel ? b1 : a1;
            u.w[2] = sel ? d0 : c0;
            u.w[3] = sel ? d1 : c1;
            pf[s] = u.v;
        }

        // O = P·V via VT rows
        float* Ob = O + (size_t)blkid * 4096;
#pragma unroll
        for (int dt = 0; dt < 4; ++dt) {
            f32x4 o = {0.f, 0.f, 0.f, 0.f};
#pragma unroll
            for (int s = 0; s < 2; ++s) {
                int vr = dt * 16 + cc;
                bf16x8 vb = *(bf16x8*)((char*)&VT[buf][0] + SWZ(vr * 128 + s * 64 + gg * 16, vr));
                o = MFMA16(pf[s], vb, o);
            }
#pragma unroll
            for (int r = 0; r < 4; ++r) {
                int q = wv * 16 + gg * 4 + r;
                Ob[q * 64 + dt * 16 + cc] = o[r];
            }
        }
    };

    // ---- pipelined main: compute(i) overlaps in-flight loads(i+1) ----
    issue(blk0);
    stageKV(0);
    stageQ();
    __syncthreads();
    issue(blk0 + 1);
#pragma unroll
    for (int i = 0; i < 4; ++i) {
        const int cur = i & 1;
        compute(cur, blk0 + i);
        if (i < 3) {
            stageKV(1 - cur);       // consumes kv/vv (waits their vmcnt here)
            stageQ();               // converts qv for block i+1
            __syncthreads();        // publish LDS set for block i+1
            if (i < 2) issue(blk0 + i + 2);   // refill; hides under compute(i+1)
        }
    }
}

extern "C" void kernel_launch(void* const* d_in, const int* in_sizes, int n_in,
                              void* d_out, int out_size, void* d_ws, size_t ws_size,
                              hipStream_t stream) {
    const float* Q = (const float*)d_in[0];
    const float* K = (const float*)d_in[1];
    const float* V = (const float*)d_in[2];
    const float* M = (const float*)d_in[3];
    float* O = (float*)d_out;
    int nblk = in_sizes[0] / 4096;       // 3072
    int grid = nblk / 4;                 // 768 = exactly 3 WG/CU (persistent)
    lsa_kernel<<<grid, 256, 0, stream>>>(Q, K, V, M, O);
}

// Round 5
// 35.958 us; speedup vs baseline: 1.1446x; 1.0101x over previous
//
#include <hip/hip_runtime.h>

// LocalSelfAttention: bs=4, h=12, s=4096, d=64, BLOCK=64 -> 3072 independent
// 64x64x64 block-attention problems. fp32 in/out.
// R0 35.9us / R2 36.6 / R3 36.3 -- occupancy (32-55%), barriers (2/1),
// pipelining: all varied, timing flat. Invariant left: LDS pipe traffic
// (24 writes + 16 b128 reads + 16 bpermute per thread, 3.15M conflict cyc
// from the VT 2B scatter). R4: V never touches LDS -- PV B-frags load
// DIRECTLY from global (V[s*32+gg*8+j][dt*16+cc] is 16-lane-contiguous,
// j-stride 256B -> imm offsets), L1/L2-resident, one-dt-ahead prefetch.
// LDS = K hi/lo + mask only (16.5KB), single barrier.

typedef __attribute__((ext_vector_type(8))) short bf16x8;   // 8 bf16 = 4 VGPR
typedef __attribute__((ext_vector_type(4))) float f32x4;    // MFMA 16x16 acc
typedef __attribute__((ext_vector_type(4))) unsigned short us4; // 8B LDS store

#define MFMA16(a, b, c) __builtin_amdgcn_mfma_f32_16x16x32_bf16((a), (b), (c), 0, 0, 0)
// XOR swizzle (guide §6 G4) for the K tile (row stride 128B).
#define SWZ(byteoff, row) ((byteoff) ^ (((row) & 7) << 4))

static __device__ __forceinline__ unsigned short f2bf(float x) {
    union { float f; unsigned int u; } v; v.f = x;
    unsigned int r = v.u + 0x7fffu + ((v.u >> 16) & 1u);   // RNE
    return (unsigned short)(r >> 16);
}
static __device__ __forceinline__ float bf2f(unsigned short b) {
    union { float f; unsigned int u; } v; v.u = ((unsigned int)b) << 16;
    return v.f;
}

// One WG (4 waves) per (b,h,block); wave = 16-query strip.
// S^T = K·Q^T (hi/lo split); softmax in-lane + 2 shuffles; P re-frag by
// 16 in-wave shuffles; PV B-operand straight from global.
__global__ __launch_bounds__(256) void lsa_kernel(
    const float* __restrict__ Q, const float* __restrict__ K,
    const float* __restrict__ V, const float* __restrict__ M,
    float* __restrict__ O)
{
    __shared__ unsigned short Kh[4096];   // K bf16 hi [key][d], swizzled
    __shared__ unsigned short Kl[4096];   // K bf16 lo
    __shared__ float maskv[64];

    const int tid  = threadIdx.x;
    const int gid  = blockIdx.x;
    const size_t base = (size_t)gid * 4096;

    const int lane = tid & 63;
    const int wv   = tid >> 6;
    const int cc   = lane & 15;
    const int gg   = lane >> 4;
    const int qrow = wv * 16 + cc;

    // ---- issue K staging loads + Q fragment loads ----
    const float4* Kg = (const float4*)(K + base);
    float4 kv[4];
#pragma unroll
    for (int it = 0; it < 4; ++it) kv[it] = Kg[tid + it * 256];

    bf16x8 qfh[2], qfl[2];
#pragma unroll
    for (int s = 0; s < 2; ++s) {
        const float* qp = Q + base + (size_t)qrow * 64 + s * 32 + gg * 8;
        float4 f0 = *(const float4*)qp;
        float4 f1 = *(const float4*)(qp + 4);
        float f[8] = {f0.x, f0.y, f0.z, f0.w, f1.x, f1.y, f1.z, f1.w};
        bf16x8 h, l;
#pragma unroll
        for (int j = 0; j < 8; ++j) {
            unsigned short hb = f2bf(f[j]);
            h[j] = (short)hb;
            l[j] = (short)f2bf(f[j] - bf2f(hb));
        }
        qfh[s] = h; qfl[s] = l;
    }
    if (tid < 64) {
        int b = gid / 768;
        int blk = gid & 63;
        maskv[tid] = M[(size_t)b * 4096 + blk * 64 + tid];
    }

    // ---- stage K hi/lo into LDS (8B stores, swizzled, conflict-free) ----
#pragma unroll
    for (int it = 0; it < 4; ++it) {
        int i   = tid + it * 256;
        int row = i >> 4;
        int cb  = (i & 15) * 8;
        float4 x = kv[it];
        us4 h, l;
        unsigned short hb;
        hb = f2bf(x.x); h.x = hb; l.x = f2bf(x.x - bf2f(hb));
        hb = f2bf(x.y); h.y = hb; l.y = f2bf(x.y - bf2f(hb));
        hb = f2bf(x.z); h.z = hb; l.z = f2bf(x.z - bf2f(hb));
        hb = f2bf(x.w); h.w = hb; l.w = f2bf(x.w - bf2f(hb));
        int by = SWZ(row * 128 + cb, row);
        *(us4*)((char*)Kh + by) = h;
        *(us4*)((char*)Kl + by) = l;
    }
    __syncthreads();   // the only barrier

    // ---- S^T = K·Q^T (hi/lo 3-term); C: col=cc=q, key-local=gg*4+reg ----
    float sc[16];
#pragma unroll
    for (int kt = 0; kt < 4; ++kt) {
        f32x4 acc = {0.f, 0.f, 0.f, 0.f};
        int krow = kt * 16 + cc;
#pragma unroll
        for (int s = 0; s < 2; ++s) {
            int by = SWZ(krow * 128 + s * 64 + gg * 16, krow);
            bf16x8 ah = *(bf16x8*)((char*)Kh + by);
            bf16x8 al = *(bf16x8*)((char*)Kl + by);
            acc = MFMA16(ah, qfh[s], acc);
            acc = MFMA16(ah, qfl[s], acc);
            acc = MFMA16(al, qfh[s], acc);
        }
#pragma unroll
        for (int r = 0; r < 4; ++r) sc[kt * 4 + r] = acc[r];
    }

    // ---- prefetch V frags for dt=0 while softmax runs ----
    // B-frag element j (of half s) = V[s*32+gg*8+j][dt*16+cc]:
    // 16-lane contiguous, j-stride 64 floats -> imm offsets.
    const float* Vb = V + base;
    float vf[16], vn[16];
    {
        const float* p0 = Vb + (size_t)(0 * 32 + gg * 8) * 64 + 0 * 16 + cc;
        const float* p1 = Vb + (size_t)(1 * 32 + gg * 8) * 64 + 0 * 16 + cc;
#pragma unroll
        for (int j = 0; j < 8; ++j) { vf[j] = p0[j * 64]; vf[8 + j] = p1[j * 64]; }
    }

    // ---- mask + softmax (lane: one query, 16 of 64 keys) ----
    float mx = -3.0e38f;
#pragma unroll
    for (int kt = 0; kt < 4; ++kt)
#pragma unroll
        for (int r = 0; r < 4; ++r) {
            int key = kt * 16 + gg * 4 + r;
            float sv = sc[kt * 4 + r] + (maskv[key] == 0.f ? -10000.f : 0.f);
            sc[kt * 4 + r] = sv;
            mx = fmaxf(mx, sv);
        }
    mx = fmaxf(mx, __shfl_xor(mx, 16));
    mx = fmaxf(mx, __shfl_xor(mx, 32));
    float sum = 0.f;
#pragma unroll
    for (int i = 0; i < 16; ++i) { sc[i] = __expf(sc[i] - mx); sum += sc[i]; }
    sum += __shfl_xor(sum, 16);
    sum += __shfl_xor(sum, 32);
    float inv = (maskv[qrow] == 0.f ? 0.f : 1.f) / sum;

    // ---- P re-fragmentation in-wave (R1 derivation) ----
    unsigned int pku[8];
#pragma unroll
    for (int kt = 0; kt < 4; ++kt) {
        unsigned int e0 = f2bf(sc[kt * 4 + 0] * inv);
        unsigned int e1 = f2bf(sc[kt * 4 + 1] * inv);
        unsigned int e2 = f2bf(sc[kt * 4 + 2] * inv);
        unsigned int e3 = f2bf(sc[kt * 4 + 3] * inv);
        pku[kt * 2 + 0] = e0 | (e1 << 16);
        pku[kt * 2 + 1] = e2 | (e3 << 16);
    }
    const int src0 = ((2 * gg) & 3) * 16 + cc;
    const int src1 = ((2 * gg + 1) & 3) * 16 + cc;
    const bool sel = (gg >> 1) & 1;
    bf16x8 pf[2];
#pragma unroll
    for (int s = 0; s < 2; ++s) {
        unsigned int a0 = (unsigned)__shfl((int)pku[4 * s + 0], src0);
        unsigned int a1 = (unsigned)__shfl((int)pku[4 * s + 1], src0);
        unsigned int b0 = (unsigned)__shfl((int)pku[4 * s + 2], src0);
        unsigned int b1 = (unsigned)__shfl((int)pku[4 * s + 3], src0);
        unsigned int c0 = (unsigned)__shfl((int)pku[4 * s + 0], src1);
        unsigned int c1 = (unsigned)__shfl((int)pku[4 * s + 1], src1);
        unsigned int d0 = (unsigned)__shfl((int)pku[4 * s + 2], src1);
        unsigned int d1 = (unsigned)__shfl((int)pku[4 * s + 3], src1);
        union { unsigned int w[4]; bf16x8 v; } u;
        u.w[0] = sel ? b0 : a0;
        u.w[1] = sel ? b1 : a1;
        u.w[2] = sel ? d0 : c0;
        u.w[3] = sel ? d1 : c1;
        pf[s] = u.v;
    }

    // ---- O = P·V, V frags from global, one-dt-ahead prefetch ----
    float* Ob = O + base;
#pragma unroll
    for (int dt = 0; dt < 4; ++dt) {
        if (dt < 3) {
            const float* p0 = Vb + (size_t)(0 * 32 + gg * 8) * 64 + (dt + 1) * 16 + cc;
            const float* p1 = Vb + (size_t)(1 * 32 + gg * 8) * 64 + (dt + 1) * 16 + cc;
#pragma unroll
            for (int j = 0; j < 8; ++j) { vn[j] = p0[j * 64]; vn[8 + j] = p1[j * 64]; }
        }
        bf16x8 vb0, vb1;
#pragma unroll
        for (int j = 0; j < 8; ++j) {
            vb0[j] = (short)f2bf(vf[j]);
            vb1[j] = (short)f2bf(vf[8 + j]);
        }
        f32x4 o = {0.f, 0.f, 0.f, 0.f};
        o = MFMA16(pf[0], vb0, o);
        o = MFMA16(pf[1], vb1, o);
#pragma unroll
        for (int r = 0; r < 4; ++r) {
            int q = wv * 16 + gg * 4 + r;
            Ob[q * 64 + dt * 16 + cc] = o[r];
        }
#pragma unroll
        for (int j = 0; j < 16; ++j) vf[j] = vn[j];   // SSA-renamed, free
    }
}

extern "C" void kernel_launch(void* const* d_in, const int* in_sizes, int n_in,
                              void* d_out, int out_size, void* d_ws, size_t ws_size,
                              hipStream_t stream) {
    const float* Q = (const float*)d_in[0];
    const float* K = (const float*)d_in[1];
    const float* V = (const float*)d_in[2];
    const float* M = (const float*)d_in[3];
    float* O = (float*)d_out;
    int grid = in_sizes[0] / 4096;   // 3072
    lsa_kernel<<<grid, 256, 0, stream>>>(Q, K, V, M, O);
}